// Round 2
// baseline (1014.699 us; speedup 1.0000x reference)
//
#include <hip/hip_runtime.h>
#include <math.h>

#define N_NODES 200000
#define N_HE    100000
#define NNZ     1000000
#define F_RAW   29
#define N_MACRO 512
#define SLOPE   0.1f
#define NB_SCAN 196   // ceil(200000/1024)

__device__ __forceinline__ float lrelu(float v) { return v >= 0.f ? v : SLOPE * v; }

// ---------- fills ----------
__global__ __launch_bounds__(256) void fill_f32(float* p, long long n, float v) {
    long long i = (long long)blockIdx.x * blockDim.x + threadIdx.x;
    long long st = (long long)gridDim.x * blockDim.x;
    for (; i < n; i += st) p[i] = v;
}

__global__ __launch_bounds__(256) void k_ismacro(const int* __restrict__ mi, float* __restrict__ ismacro) {
    int i = blockIdx.x * blockDim.x + threadIdx.x;
    if (i < N_MACRO) ismacro[mi[i]] = 1.0f;
}

// ---------- K0: xl = h @ W1 + b1 ; xn_att = xl . att[:64] ----------
__global__ __launch_bounds__(256) void k_xl(
    const float* __restrict__ x, const float* __restrict__ fake_pos,
    const float* __restrict__ ismacro,
    const float* __restrict__ W1, const float* __restrict__ b1,
    const float* __restrict__ att,
    float* __restrict__ xl, float* __restrict__ xn_att)
{
    __shared__ float sW[32 * 64];
    __shared__ float sb[64];
    __shared__ float sa[64];
    for (int i = threadIdx.x; i < 32 * 64; i += 256) sW[i] = W1[i];
    if (threadIdx.x < 64) { sb[threadIdx.x] = b1[threadIdx.x]; sa[threadIdx.x] = att[threadIdx.x]; }
    __syncthreads();
    const int lane = threadIdx.x & 63;
    const int wave = threadIdx.x >> 6;
    int w = blockIdx.x * 4 + wave;
    int nw = gridDim.x * 4;
    for (int n = w; n < N_NODES; n += nw) {
        float acc = sb[lane];
        const float* xr = x + (size_t)n * F_RAW;
        #pragma unroll
        for (int k = 0; k < F_RAW; k++) acc += xr[k] * sW[k * 64 + lane];
        acc += fake_pos[2 * n]     * sW[29 * 64 + lane];
        acc += fake_pos[2 * n + 1] * sW[30 * 64 + lane];
        acc += ismacro[n]          * sW[31 * 64 + lane];
        xl[(size_t)n * 64 + lane] = acc;
        float r = acc * sa[lane];
        #pragma unroll
        for (int o = 32; o > 0; o >>= 1) r += __shfl_down(r, o, 64);
        if (lane == 0) xn_att[n] = r;
    }
}

// ---------- K1: pin -> hyperedge scatter (sum + he degree) + node degree count ----------
__global__ __launch_bounds__(256) void k_pin2he(
    const int* __restrict__ nidx, const int* __restrict__ hidx,
    const float* __restrict__ pinf, const float* __restrict__ Wpin,
    const float* __restrict__ xl,
    float* __restrict__ e_feat, float* __restrict__ deg_e, int* __restrict__ cnt)
{
    const int lane = threadIdx.x & 63;
    int w = (blockIdx.x * blockDim.x + threadIdx.x) >> 6;
    int nw = (gridDim.x * blockDim.x) >> 6;
    float w0 = Wpin[lane], w1 = Wpin[64 + lane], w2 = Wpin[128 + lane], w3 = Wpin[192 + lane];
    for (int p = w; p < NNZ; p += nw) {
        int n = nidx[p], e = hidx[p];
        float p0 = pinf[4 * p], p1 = pinf[4 * p + 1], p2 = pinf[4 * p + 2], p3 = pinf[4 * p + 3];
        float v = xl[(size_t)n * 64 + lane] + p0 * w0 + p1 * w1 + p2 * w2 + p3 * w3;
        atomicAdd(&e_feat[(size_t)e * 64 + lane], v);
        if (lane == 0) {
            atomicAdd(&deg_e[e], 1.0f);
            atomicAdd(&cnt[n], 1);
        }
    }
}

// ---------- K2: e_feat /= max(deg,1) ; e_att = e_feat . att[64:] ----------
__global__ __launch_bounds__(256) void k_he_fin(
    float* __restrict__ e_feat, const float* __restrict__ deg_e,
    const float* __restrict__ att, float* __restrict__ e_att)
{
    const int lane = threadIdx.x & 63;
    int w = (blockIdx.x * blockDim.x + threadIdx.x) >> 6;
    int nw = (gridDim.x * blockDim.x) >> 6;
    float ac = att[64 + lane];
    for (int e = w; e < N_HE; e += nw) {
        float d = fmaxf(deg_e[e], 1.0f);
        size_t o = (size_t)e * 64 + lane;
        float v = e_feat[o] / d;
        e_feat[o] = v;
        float r = v * ac;
        #pragma unroll
        for (int of = 32; of > 0; of >>= 1) r += __shfl_down(r, of, 64);
        if (lane == 0) e_att[e] = r;
    }
}

// ---------- CSR build: scan of cnt -> row_ptr ----------
__global__ __launch_bounds__(256) void k_scan1(const int* __restrict__ cnt,
                                               int* __restrict__ row_ptr, int* __restrict__ partials)
{
    __shared__ int sA[256], sB[256];
    const int t = threadIdx.x;
    const int base = blockIdx.x * 1024 + t * 4;
    int v0 = base + 0 < N_NODES ? cnt[base + 0] : 0;
    int v1 = base + 1 < N_NODES ? cnt[base + 1] : 0;
    int v2 = base + 2 < N_NODES ? cnt[base + 2] : 0;
    int v3 = base + 3 < N_NODES ? cnt[base + 3] : 0;
    sA[t] = v0 + v1 + v2 + v3;
    __syncthreads();
    int* src = sA; int* dst = sB;
    for (int off = 1; off < 256; off <<= 1) {
        int v = src[t];
        if (t >= off) v += src[t - off];
        dst[t] = v;
        __syncthreads();
        int* tmp = src; src = dst; dst = tmp;
    }
    int excl = t > 0 ? src[t - 1] : 0;
    if (base + 0 < N_NODES) row_ptr[base + 0] = excl;
    if (base + 1 < N_NODES) row_ptr[base + 1] = excl + v0;
    if (base + 2 < N_NODES) row_ptr[base + 2] = excl + v0 + v1;
    if (base + 3 < N_NODES) row_ptr[base + 3] = excl + v0 + v1 + v2;
    if (t == 255) partials[blockIdx.x] = src[255];
}

__global__ __launch_bounds__(64) void k_scan2(int* __restrict__ partials)
{
    if (threadIdx.x == 0) {
        int run = 0;
        for (int b = 0; b < NB_SCAN; b++) { int v = partials[b]; partials[b] = run; run += v; }
        partials[NB_SCAN] = run;
    }
}

__global__ __launch_bounds__(256) void k_scan3(int* __restrict__ row_ptr, const int* __restrict__ partials)
{
    const int base = blockIdx.x * 1024 + threadIdx.x * 4;
    int add = partials[blockIdx.x];
    #pragma unroll
    for (int k = 0; k < 4; k++)
        if (base + k < N_NODES) row_ptr[base + k] += add;
    if (blockIdx.x == 0 && threadIdx.x == 0) row_ptr[N_NODES] = partials[NB_SCAN];
}

// ---------- K3: scatter pins into CSR (order within row arbitrary) ----------
__global__ __launch_bounds__(256) void k_scatter(
    const int* __restrict__ nidx, const int* __restrict__ hidx,
    const int* __restrict__ row_ptr, int* __restrict__ cursor, int* __restrict__ csr_e)
{
    int i = blockIdx.x * blockDim.x + threadIdx.x;
    int st = gridDim.x * blockDim.x;
    for (int p = i; p < NNZ; p += st) {
        int n = nidx[p];
        int pos = row_ptr[n] + atomicAdd(&cursor[n], 1);
        csr_e[pos] = hidx[p];
    }
}

// ---------- K4: fused attention-softmax + PNA stats + post GEMM + lrelu + pool ----------
__global__ __launch_bounds__(256) void k_fused(
    const int* __restrict__ row_ptr, const int* __restrict__ csr_e,
    const float* __restrict__ xn_att, const float* __restrict__ e_att,
    const float* __restrict__ e_feat,
    const float* __restrict__ Wpost, const float* __restrict__ bpost,
    float* __restrict__ hx, float* __restrict__ sum_all)
{
    __shared__ float scat[32 * 260];   // 32 nodes x 256 cat, stride 260
    __shared__ float sred[16][68];
    const int lane = threadIdx.x & 63;
    const int wave = threadIdx.x >> 6;
    const int cg = threadIdx.x & 15;   // channel group: channels 4cg..4cg+3
    const int ng = threadIdx.x >> 4;   // nodes 2ng, 2ng+1
    const float4* Wp4 = (const float4*)Wpost;
    float4 bp = ((const float4*)bpost)[cg];
    float4 pool = make_float4(0.f, 0.f, 0.f, 0.f);
    const int nbatches = N_NODES / 32;  // 6250
    for (int b = blockIdx.x; b < nbatches; b += gridDim.x) {
        const int base = b * 32;
        __syncthreads();
        // phase A: per-node softmax + PNA stats -> LDS (each wave: 8 nodes)
        for (int i = 0; i < 8; i++) {
            int j = wave * 8 + i;
            int n = base + j;
            int start = row_ptr[n];
            int deg = row_ptr[n + 1] - start;
            float xn = xn_att[n];
            // pass 1: max + denom (lane-parallel over pins)
            float am = -INFINITY;
            for (int t = lane; t < deg; t += 64) {
                float a = lrelu(xn + e_att[csr_e[start + t]]);
                am = fmaxf(am, a);
            }
            #pragma unroll
            for (int o = 32; o > 0; o >>= 1) am = fmaxf(am, __shfl_xor(am, o, 64));
            float m = (deg > 0) ? am : 0.f;
            float exs = 0.f;
            for (int t = lane; t < deg; t += 64) {
                float a = lrelu(xn + e_att[csr_e[start + t]]);
                exs += __expf(a - m);
            }
            #pragma unroll
            for (int o = 32; o > 0; o >>= 1) exs += __shfl_xor(exs, o, 64);
            float inv_den = 1.f / (exs + 1e-16f);
            // pass 2: sequential over pins, all lanes gather the e_feat row
            float s = 0.f, sq = 0.f, mx = -INFINITY, mn = INFINITY;
            for (int t = 0; t < deg; t++) {
                int e = csr_e[start + t];
                float a = lrelu(xn + e_att[e]);
                float alpha = __expf(a - m) * inv_den;
                float v = e_feat[(size_t)e * 64 + lane] * alpha;
                s += v; sq += v * v;
                mx = fmaxf(mx, v); mn = fminf(mn, v);
            }
            float dc = (float)(deg > 0 ? deg : 1);
            float mean = s / dc;
            float sqm = sq / dc;
            float stdv = sqrtf(fmaxf(sqm - mean * mean, 0.f) + 1e-12f);
            float mxv = deg > 0 ? mx : 0.f;
            float mnv = deg > 0 ? mn : 0.f;
            float* row = &scat[j * 260];
            row[lane] = mean;
            row[64 + lane] = mxv;
            row[128 + lane] = mnv;
            row[192 + lane] = stdv;
        }
        __syncthreads();
        // phase B: 4ch x 2node register-tile GEMM, W from global (L1-hot)
        float4 a0 = bp, a1 = bp;
        const float* r0 = &scat[(2 * ng) * 260];
        const float* r1 = &scat[(2 * ng + 1) * 260];
        #pragma unroll 2
        for (int k = 0; k < 256; k += 4) {
            float4 c0 = *(const float4*)&r0[k];
            float4 c1 = *(const float4*)&r1[k];
            float4 w0 = Wp4[(k + 0) * 16 + cg];
            float4 w1 = Wp4[(k + 1) * 16 + cg];
            float4 w2 = Wp4[(k + 2) * 16 + cg];
            float4 w3 = Wp4[(k + 3) * 16 + cg];
            a0.x += c0.x * w0.x + c0.y * w1.x + c0.z * w2.x + c0.w * w3.x;
            a0.y += c0.x * w0.y + c0.y * w1.y + c0.z * w2.y + c0.w * w3.y;
            a0.z += c0.x * w0.z + c0.y * w1.z + c0.z * w2.z + c0.w * w3.z;
            a0.w += c0.x * w0.w + c0.y * w1.w + c0.z * w2.w + c0.w * w3.w;
            a1.x += c1.x * w0.x + c1.y * w1.x + c1.z * w2.x + c1.w * w3.x;
            a1.y += c1.x * w0.y + c1.y * w1.y + c1.z * w2.y + c1.w * w3.y;
            a1.z += c1.x * w0.z + c1.y * w1.z + c1.z * w2.z + c1.w * w3.z;
            a1.w += c1.x * w0.w + c1.y * w1.w + c1.z * w2.w + c1.w * w3.w;
        }
        float4 h0, h1;
        h0.x = lrelu(a0.x); h0.y = lrelu(a0.y); h0.z = lrelu(a0.z); h0.w = lrelu(a0.w);
        h1.x = lrelu(a1.x); h1.y = lrelu(a1.y); h1.z = lrelu(a1.z); h1.w = lrelu(a1.w);
        *(float4*)&hx[(size_t)(base + 2 * ng) * 64 + 4 * cg] = h0;
        *(float4*)&hx[(size_t)(base + 2 * ng + 1) * 64 + 4 * cg] = h1;
        pool.x += h0.x + h1.x; pool.y += h0.y + h1.y;
        pool.z += h0.z + h1.z; pool.w += h0.w + h1.w;
    }
    __syncthreads();
    sred[ng][4 * cg + 0] = pool.x;
    sred[ng][4 * cg + 1] = pool.y;
    sred[ng][4 * cg + 2] = pool.z;
    sred[ng][4 * cg + 3] = pool.w;
    __syncthreads();
    if (threadIdx.x < 64) {
        float t = 0.f;
        #pragma unroll
        for (int r = 0; r < 16; r++) t += sred[r][threadIdx.x];
        atomicAdd(&sum_all[threadIdx.x], t);
    }
}

// ---------- K5: macro pool + tiny MLP head ----------
__global__ __launch_bounds__(256) void k_final(
    const float* __restrict__ hx, const int* __restrict__ macro_index,
    const float* __restrict__ sum_all,
    const float* __restrict__ Wm1, const float* __restrict__ bm1,
    const float* __restrict__ Wm2, const float* __restrict__ bm2,
    const float* __restrict__ Wm3, const float* __restrict__ bm3,
    float* __restrict__ out)
{
    __shared__ float smac[64];
    __shared__ float spool[128];
    __shared__ float z1[64];
    __shared__ float z2[32];
    const int lane = threadIdx.x & 63;
    const int wave = threadIdx.x >> 6;
    if (threadIdx.x < 64) smac[threadIdx.x] = 0.f;
    __syncthreads();
    float acc = 0.f;
    for (int i = wave; i < N_MACRO; i += 4) {
        int row = macro_index[i];
        acc += hx[(size_t)row * 64 + lane];
    }
    atomicAdd(&smac[lane], acc);
    __syncthreads();
    if (threadIdx.x < 64) {
        spool[threadIdx.x] = smac[threadIdx.x] / (float)N_MACRO;
        spool[64 + threadIdx.x] = sum_all[threadIdx.x] / (float)N_NODES;
    }
    __syncthreads();
    if (threadIdx.x < 64) {
        int j = threadIdx.x;
        float a = bm1[j];
        #pragma unroll 4
        for (int k = 0; k < 128; k++) a += spool[k] * Wm1[k * 64 + j];
        z1[j] = lrelu(a);
    }
    __syncthreads();
    if (threadIdx.x < 32) {
        int j = threadIdx.x;
        float a = bm2[j];
        #pragma unroll 4
        for (int k = 0; k < 64; k++) a += z1[k] * Wm2[k * 32 + j];
        z2[j] = lrelu(a);
    }
    __syncthreads();
    if (threadIdx.x == 0) {
        float a = bm3[0];
        #pragma unroll
        for (int k = 0; k < 32; k++) a += z2[k] * Wm3[k];
        out[0] = a;
    }
}

// ---------- launch ----------
extern "C" void kernel_launch(void* const* d_in, const int* in_sizes, int n_in,
                              void* d_out, int out_size, void* d_ws, size_t ws_size,
                              hipStream_t stream)
{
    const float* x        = (const float*)d_in[0];
    const float* fake_pos = (const float*)d_in[1];
    const int*   edge     = (const int*)d_in[2];
    const float* pinf     = (const float*)d_in[3];
    const int*   macro    = (const int*)d_in[4];
    const float* W1    = (const float*)d_in[5];
    const float* b1    = (const float*)d_in[6];
    const float* Wpin  = (const float*)d_in[7];
    const float* att   = (const float*)d_in[8];
    const float* Wpost = (const float*)d_in[9];
    const float* bpost = (const float*)d_in[10];
    const float* Wm1   = (const float*)d_in[11];
    const float* bm1   = (const float*)d_in[12];
    const float* Wm2   = (const float*)d_in[13];
    const float* bm2   = (const float*)d_in[14];
    const float* Wm3   = (const float*)d_in[15];
    const float* bm3   = (const float*)d_in[16];
    float* out = (float*)d_out;

    float* ws = (float*)d_ws;
    // layout (4-byte units); zero region = [0, 7,100,064)
    float* e_feat  = ws;                        // 6,400,000
    float* deg_e   = ws + 6400000;              //   100,000
    float* ismacro = ws + 6500000;              //   200,000
    float* sum_all = ws + 6700000;              //        64
    int*   cnt     = (int*)(ws + 6700064);      //   200,000
    int*   cursor  = (int*)(ws + 6900064);      //   200,000
    // end zero region (7,100,064)
    int*   row_ptr  = (int*)(ws + 7100064);     //   200,001
    int*   partials = (int*)(ws + 7300096);     //       256
    int*   csr_e    = (int*)(ws + 7300352);     // 1,000,000
    float* xn_att   = ws + 8300352;             //   200,000
    float* e_att    = ws + 8500352;             //   100,000
    float* xl       = ws + 8600352;             // 12,800,000 (reused as hx)
    // total: 21,400,352 floats = 85.6 MB

    const int* nidx = edge;
    const int* hidx = edge + NNZ;

    fill_f32<<<2048, 256, 0, stream>>>(ws, 7100064LL, 0.f);
    k_ismacro<<<2, 256, 0, stream>>>(macro, ismacro);
    k_xl<<<2048, 256, 0, stream>>>(x, fake_pos, ismacro, W1, b1, att, xl, xn_att);
    k_pin2he<<<4096, 256, 0, stream>>>(nidx, hidx, pinf, Wpin, xl, e_feat, deg_e, cnt);
    k_he_fin<<<1024, 256, 0, stream>>>(e_feat, deg_e, att, e_att);
    k_scan1<<<NB_SCAN, 256, 0, stream>>>(cnt, row_ptr, partials);
    k_scan2<<<1, 64, 0, stream>>>(partials);
    k_scan3<<<NB_SCAN, 256, 0, stream>>>(row_ptr, partials);
    k_scatter<<<2048, 256, 0, stream>>>(nidx, hidx, row_ptr, cursor, csr_e);
    k_fused<<<1024, 256, 0, stream>>>(row_ptr, csr_e, xn_att, e_att, e_feat, Wpost, bpost, xl, sum_all);
    k_final<<<1, 256, 0, stream>>>(xl, macro, sum_all, Wm1, bm1, Wm2, bm2, Wm3, bm3, out);
}

// Round 3
// 989.776 us; speedup vs baseline: 1.0252x; 1.0252x over previous
//
#include <hip/hip_runtime.h>
#include <math.h>

#define N_NODES 200000
#define N_HE    100000
#define NNZ     1000000
#define F_RAW   29
#define N_MACRO 512
#define SLOPE   0.1f
#define L_TOTAL (N_NODES + N_HE)   // 300000 combined counters
#define NB_SCAN 293                // ceil(300000/1024)

__device__ __forceinline__ float lrelu(float v) { return v >= 0.f ? v : SLOPE * v; }

// ---------- fills ----------
__global__ __launch_bounds__(256) void fill_f32(float* p, long long n, float v) {
    long long i = (long long)blockIdx.x * blockDim.x + threadIdx.x;
    long long st = (long long)gridDim.x * blockDim.x;
    for (; i < n; i += st) p[i] = v;
}

__global__ __launch_bounds__(256) void k_ismacro(const int* __restrict__ mi, float* __restrict__ ismacro) {
    int i = blockIdx.x * blockDim.x + threadIdx.x;
    if (i < N_MACRO) ismacro[mi[i]] = 1.0f;
}

// ---------- K0: xl = h @ W1 + b1 ; xn_att = xl . att[:64] ----------
__global__ __launch_bounds__(256) void k_xl(
    const float* __restrict__ x, const float* __restrict__ fake_pos,
    const float* __restrict__ ismacro,
    const float* __restrict__ W1, const float* __restrict__ b1,
    const float* __restrict__ att,
    float* __restrict__ xl, float* __restrict__ xn_att)
{
    __shared__ float sW[32 * 64];
    __shared__ float sb[64];
    __shared__ float sa[64];
    for (int i = threadIdx.x; i < 32 * 64; i += 256) sW[i] = W1[i];
    if (threadIdx.x < 64) { sb[threadIdx.x] = b1[threadIdx.x]; sa[threadIdx.x] = att[threadIdx.x]; }
    __syncthreads();
    const int lane = threadIdx.x & 63;
    const int wave = threadIdx.x >> 6;
    int w = blockIdx.x * 4 + wave;
    int nw = gridDim.x * 4;
    for (int n = w; n < N_NODES; n += nw) {
        float acc = sb[lane];
        const float* xr = x + (size_t)n * F_RAW;
        #pragma unroll
        for (int k = 0; k < F_RAW; k++) acc += xr[k] * sW[k * 64 + lane];
        acc += fake_pos[2 * n]     * sW[29 * 64 + lane];
        acc += fake_pos[2 * n + 1] * sW[30 * 64 + lane];
        acc += ismacro[n]          * sW[31 * 64 + lane];
        xl[(size_t)n * 64 + lane] = acc;
        float r = acc * sa[lane];
        #pragma unroll
        for (int o = 32; o > 0; o >>= 1) r += __shfl_down(r, o, 64);
        if (lane == 0) xn_att[n] = r;
    }
}

// ---------- count pins per node and per hyperedge (combined array) ----------
__global__ __launch_bounds__(256) void k_count(
    const int* __restrict__ nidx, const int* __restrict__ hidx, int* __restrict__ cnt)
{
    int i = blockIdx.x * blockDim.x + threadIdx.x;
    int st = gridDim.x * blockDim.x;
    for (int p = i; p < NNZ; p += st) {
        atomicAdd(&cnt[nidx[p]], 1);
        atomicAdd(&cnt[N_NODES + hidx[p]], 1);
    }
}

// ---------- scan of cnt (length L_TOTAL) -> row_ptr ----------
__global__ __launch_bounds__(256) void k_scan1(const int* __restrict__ cnt,
                                               int* __restrict__ row_ptr, int* __restrict__ partials)
{
    __shared__ int sA[256], sB[256];
    const int t = threadIdx.x;
    const int base = blockIdx.x * 1024 + t * 4;
    int v0 = base + 0 < L_TOTAL ? cnt[base + 0] : 0;
    int v1 = base + 1 < L_TOTAL ? cnt[base + 1] : 0;
    int v2 = base + 2 < L_TOTAL ? cnt[base + 2] : 0;
    int v3 = base + 3 < L_TOTAL ? cnt[base + 3] : 0;
    sA[t] = v0 + v1 + v2 + v3;
    __syncthreads();
    int* src = sA; int* dst = sB;
    for (int off = 1; off < 256; off <<= 1) {
        int v = src[t];
        if (t >= off) v += src[t - off];
        dst[t] = v;
        __syncthreads();
        int* tmp = src; src = dst; dst = tmp;
    }
    int excl = t > 0 ? src[t - 1] : 0;
    if (base + 0 < L_TOTAL) row_ptr[base + 0] = excl;
    if (base + 1 < L_TOTAL) row_ptr[base + 1] = excl + v0;
    if (base + 2 < L_TOTAL) row_ptr[base + 2] = excl + v0 + v1;
    if (base + 3 < L_TOTAL) row_ptr[base + 3] = excl + v0 + v1 + v2;
    if (t == 255) partials[blockIdx.x] = src[255];
}

__global__ __launch_bounds__(512) void k_scan2(int* __restrict__ partials)
{
    __shared__ int sA[512], sB[512];
    const int t = threadIdx.x;
    sA[t] = t < NB_SCAN ? partials[t] : 0;
    __syncthreads();
    int* src = sA; int* dst = sB;
    for (int off = 1; off < 512; off <<= 1) {
        int v = src[t];
        if (t >= off) v += src[t - off];
        dst[t] = v;
        __syncthreads();
        int* tmp = src; src = dst; dst = tmp;
    }
    if (t < NB_SCAN) partials[t] = t > 0 ? src[t - 1] : 0;
    if (t == 0) partials[NB_SCAN] = src[511];
}

__global__ __launch_bounds__(256) void k_scan3(int* __restrict__ row_ptr, const int* __restrict__ partials)
{
    const int base = blockIdx.x * 1024 + threadIdx.x * 4;
    int add = partials[blockIdx.x];
    #pragma unroll
    for (int k = 0; k < 4; k++)
        if (base + k < L_TOTAL) row_ptr[base + k] += add;
    if (blockIdx.x == 0 && threadIdx.x == 0) row_ptr[L_TOTAL] = partials[NB_SCAN];
}

// ---------- scatter pins into both CSRs (node side: he id; he side: pin id) ----------
// uses atomicSub on cnt (which still holds counts) so no cursor zeroing needed
__global__ __launch_bounds__(256) void k_scatter(
    const int* __restrict__ nidx, const int* __restrict__ hidx,
    const int* __restrict__ row_ptr, int* __restrict__ cnt, int* __restrict__ csr)
{
    int i = blockIdx.x * blockDim.x + threadIdx.x;
    int st = gridDim.x * blockDim.x;
    for (int p = i; p < NNZ; p += st) {
        int n = nidx[p], e = hidx[p];
        int pn = row_ptr[n] + atomicSub(&cnt[n], 1) - 1;
        csr[pn] = e;
        int pe = row_ptr[N_NODES + e] + atomicSub(&cnt[N_NODES + e], 1) - 1;
        csr[pe] = p;
    }
}

// ---------- he-side gather: e_feat mean + e_att dot (no atomics) ----------
__global__ __launch_bounds__(256) void k_he_agg(
    const int* __restrict__ row_ptr, const int* __restrict__ csr,
    const int* __restrict__ nidx,
    const float* __restrict__ pinf, const float* __restrict__ Wpin,
    const float* __restrict__ xl, const float* __restrict__ att,
    float* __restrict__ e_feat, float* __restrict__ e_att)
{
    const int lane = threadIdx.x & 63;
    int w = (blockIdx.x * blockDim.x + threadIdx.x) >> 6;
    int nw = (gridDim.x * blockDim.x) >> 6;
    float w0 = Wpin[lane], w1 = Wpin[64 + lane], w2 = Wpin[128 + lane], w3 = Wpin[192 + lane];
    float ac = att[64 + lane];
    const float4* pf4 = (const float4*)pinf;
    for (int e = w; e < N_HE; e += nw) {
        int start = row_ptr[N_NODES + e];
        int deg = row_ptr[N_NODES + e + 1] - start;
        float acc = 0.f;
        int t = 0;
        for (; t + 4 <= deg; t += 4) {
            int p0 = csr[start + t], p1 = csr[start + t + 1];
            int p2 = csr[start + t + 2], p3 = csr[start + t + 3];
            int n0 = nidx[p0], n1 = nidx[p1], n2 = nidx[p2], n3 = nidx[p3];
            float v0 = xl[(size_t)n0 * 64 + lane];
            float v1 = xl[(size_t)n1 * 64 + lane];
            float v2 = xl[(size_t)n2 * 64 + lane];
            float v3 = xl[(size_t)n3 * 64 + lane];
            float4 q0 = pf4[p0], q1 = pf4[p1], q2 = pf4[p2], q3 = pf4[p3];
            acc += v0 + q0.x * w0 + q0.y * w1 + q0.z * w2 + q0.w * w3;
            acc += v1 + q1.x * w0 + q1.y * w1 + q1.z * w2 + q1.w * w3;
            acc += v2 + q2.x * w0 + q2.y * w1 + q2.z * w2 + q2.w * w3;
            acc += v3 + q3.x * w0 + q3.y * w1 + q3.z * w2 + q3.w * w3;
        }
        for (; t < deg; t++) {
            int p = csr[start + t];
            int n = nidx[p];
            float4 q = pf4[p];
            acc += xl[(size_t)n * 64 + lane] + q.x * w0 + q.y * w1 + q.z * w2 + q.w * w3;
        }
        float d = (float)(deg > 0 ? deg : 1);
        float v = acc / d;
        e_feat[(size_t)e * 64 + lane] = v;
        float r = v * ac;
        #pragma unroll
        for (int o = 32; o > 0; o >>= 1) r += __shfl_down(r, o, 64);
        if (lane == 0) e_att[e] = r;
    }
}

// ---------- fused softmax + PNA + post GEMM + lrelu + pool ----------
__global__ __launch_bounds__(256) void k_fused(
    const int* __restrict__ row_ptr, const int* __restrict__ csr,
    const float* __restrict__ xn_att, const float* __restrict__ e_att,
    const float* __restrict__ e_feat,
    const float* __restrict__ Wpost, const float* __restrict__ bpost,
    float* __restrict__ hx, float* __restrict__ sum_all)
{
    __shared__ float scat[16 * 260];   // 16 nodes x 256 cat, stride 260
    __shared__ float sred[16][68];
    const int lane = threadIdx.x & 63;
    const int wave = threadIdx.x >> 6;
    const int g  = lane >> 4;          // 16-lane group -> node wave*4+g (phase A0)
    const int gl = lane & 15;
    const int cg = threadIdx.x & 15;   // phase B: channels 4cg..4cg+3
    const int nd = threadIdx.x >> 4;   // phase B: node 0..15
    const float4* Wp4 = (const float4*)Wpost;
    float4 bp = ((const float4*)bpost)[cg];
    float4 pool = make_float4(0.f, 0.f, 0.f, 0.f);
    const int nbatches = N_NODES / 16;  // 12500
    for (int b = blockIdx.x; b < nbatches; b += gridDim.x) {
        const int base = b * 16;
        __syncthreads();
        // ---- A0: group-parallel softmax stats (each 16-lane group: one node) ----
        int n_g = base + wave * 4 + g;
        int st_g = row_ptr[n_g];
        int dg_g = row_ptr[n_g + 1] - st_g;
        float xn_g = xn_att[n_g];
        float am = -INFINITY;
        for (int t = gl; t < dg_g; t += 16)
            am = fmaxf(am, xn_g + e_att[csr[st_g + t]]);
        #pragma unroll
        for (int o = 8; o > 0; o >>= 1) am = fmaxf(am, __shfl_xor(am, o, 64));
        float m_g = dg_g > 0 ? lrelu(am) : 0.f;   // lrelu monotone: max(lrelu(a)) = lrelu(max a)
        float es = 0.f;
        for (int t = gl; t < dg_g; t += 16)
            es += __expf(lrelu(xn_g + e_att[csr[st_g + t]]) - m_g);
        #pragma unroll
        for (int o = 8; o > 0; o >>= 1) es += __shfl_xor(es, o, 64);
        float invd_g = 1.f / (es + 1e-16f);
        // ---- A1: per-node full-wave PNA, 4-wide chunked gathers ----
        #pragma unroll
        for (int i = 0; i < 4; i++) {
            int j = wave * 4 + i;
            int n = base + j;
            int start = row_ptr[n];
            int deg = row_ptr[n + 1] - start;
            float xn = xn_att[n];
            float m    = __shfl(m_g,    16 * i, 64);
            float invd = __shfl(invd_g, 16 * i, 64);
            float s = 0.f, sq = 0.f, mx = -INFINITY, mn = INFINITY;
            int t = 0;
            for (; t + 4 <= deg; t += 4) {
                int e0 = csr[start + t],     e1 = csr[start + t + 1];
                int e2 = csr[start + t + 2], e3 = csr[start + t + 3];
                float v0 = e_feat[(size_t)e0 * 64 + lane];
                float v1 = e_feat[(size_t)e1 * 64 + lane];
                float v2 = e_feat[(size_t)e2 * 64 + lane];
                float v3 = e_feat[(size_t)e3 * 64 + lane];
                float a0 = __expf(lrelu(xn + e_att[e0]) - m) * invd;
                float a1 = __expf(lrelu(xn + e_att[e1]) - m) * invd;
                float a2 = __expf(lrelu(xn + e_att[e2]) - m) * invd;
                float a3 = __expf(lrelu(xn + e_att[e3]) - m) * invd;
                v0 *= a0; v1 *= a1; v2 *= a2; v3 *= a3;
                s  += v0 + v1 + v2 + v3;
                sq += v0 * v0 + v1 * v1 + v2 * v2 + v3 * v3;
                mx = fmaxf(fmaxf(fmaxf(mx, v0), fmaxf(v1, v2)), v3);
                mn = fminf(fminf(fminf(mn, v0), fminf(v1, v2)), v3);
            }
            for (; t < deg; t++) {
                int e = csr[start + t];
                float v = e_feat[(size_t)e * 64 + lane] * (__expf(lrelu(xn + e_att[e]) - m) * invd);
                s += v; sq += v * v; mx = fmaxf(mx, v); mn = fminf(mn, v);
            }
            float dc = (float)(deg > 0 ? deg : 1);
            float mean = s / dc;
            float stdv = sqrtf(fmaxf(sq / dc - mean * mean, 0.f) + 1e-12f);
            float* row = &scat[j * 260];
            row[lane]        = mean;
            row[64 + lane]   = deg > 0 ? mx : 0.f;
            row[128 + lane]  = deg > 0 ? mn : 0.f;
            row[192 + lane]  = stdv;
        }
        __syncthreads();
        // ---- B: 1 node x 4 ch per thread, W from global (L1-hot) ----
        float4 a0 = bp;
        const float* r0 = &scat[nd * 260];
        #pragma unroll 4
        for (int k = 0; k < 256; k += 4) {
            float4 c  = *(const float4*)&r0[k];
            float4 w0 = Wp4[(k + 0) * 16 + cg];
            float4 w1 = Wp4[(k + 1) * 16 + cg];
            float4 w2 = Wp4[(k + 2) * 16 + cg];
            float4 w3 = Wp4[(k + 3) * 16 + cg];
            a0.x += c.x * w0.x + c.y * w1.x + c.z * w2.x + c.w * w3.x;
            a0.y += c.x * w0.y + c.y * w1.y + c.z * w2.y + c.w * w3.y;
            a0.z += c.x * w0.z + c.y * w1.z + c.z * w2.z + c.w * w3.z;
            a0.w += c.x * w0.w + c.y * w1.w + c.z * w2.w + c.w * w3.w;
        }
        float4 h;
        h.x = lrelu(a0.x); h.y = lrelu(a0.y); h.z = lrelu(a0.z); h.w = lrelu(a0.w);
        *(float4*)&hx[(size_t)(base + nd) * 64 + 4 * cg] = h;
        pool.x += h.x; pool.y += h.y; pool.z += h.z; pool.w += h.w;
    }
    __syncthreads();
    sred[nd][4 * cg + 0] = pool.x;
    sred[nd][4 * cg + 1] = pool.y;
    sred[nd][4 * cg + 2] = pool.z;
    sred[nd][4 * cg + 3] = pool.w;
    __syncthreads();
    if (threadIdx.x < 64) {
        float t = 0.f;
        #pragma unroll
        for (int r = 0; r < 16; r++) t += sred[r][threadIdx.x];
        atomicAdd(&sum_all[threadIdx.x], t);
    }
}

// ---------- macro pool + tiny MLP head ----------
__global__ __launch_bounds__(256) void k_final(
    const float* __restrict__ hx, const int* __restrict__ macro_index,
    const float* __restrict__ sum_all,
    const float* __restrict__ Wm1, const float* __restrict__ bm1,
    const float* __restrict__ Wm2, const float* __restrict__ bm2,
    const float* __restrict__ Wm3, const float* __restrict__ bm3,
    float* __restrict__ out)
{
    __shared__ float smac[64];
    __shared__ float spool[128];
    __shared__ float z1[64];
    __shared__ float z2[32];
    const int lane = threadIdx.x & 63;
    const int wave = threadIdx.x >> 6;
    if (threadIdx.x < 64) smac[threadIdx.x] = 0.f;
    __syncthreads();
    float acc = 0.f;
    for (int i = wave; i < N_MACRO; i += 4) {
        int row = macro_index[i];
        acc += hx[(size_t)row * 64 + lane];
    }
    atomicAdd(&smac[lane], acc);
    __syncthreads();
    if (threadIdx.x < 64) {
        spool[threadIdx.x] = smac[threadIdx.x] / (float)N_MACRO;
        spool[64 + threadIdx.x] = sum_all[threadIdx.x] / (float)N_NODES;
    }
    __syncthreads();
    if (threadIdx.x < 64) {
        int j = threadIdx.x;
        float a = bm1[j];
        #pragma unroll 4
        for (int k = 0; k < 128; k++) a += spool[k] * Wm1[k * 64 + j];
        z1[j] = lrelu(a);
    }
    __syncthreads();
    if (threadIdx.x < 32) {
        int j = threadIdx.x;
        float a = bm2[j];
        #pragma unroll 4
        for (int k = 0; k < 64; k++) a += z1[k] * Wm2[k * 32 + j];
        z2[j] = lrelu(a);
    }
    __syncthreads();
    if (threadIdx.x == 0) {
        float a = bm3[0];
        #pragma unroll
        for (int k = 0; k < 32; k++) a += z2[k] * Wm3[k];
        out[0] = a;
    }
}

// ---------- launch ----------
extern "C" void kernel_launch(void* const* d_in, const int* in_sizes, int n_in,
                              void* d_out, int out_size, void* d_ws, size_t ws_size,
                              hipStream_t stream)
{
    const float* x        = (const float*)d_in[0];
    const float* fake_pos = (const float*)d_in[1];
    const int*   edge     = (const int*)d_in[2];
    const float* pinf     = (const float*)d_in[3];
    const int*   macro    = (const int*)d_in[4];
    const float* W1    = (const float*)d_in[5];
    const float* b1    = (const float*)d_in[6];
    const float* Wpin  = (const float*)d_in[7];
    const float* att   = (const float*)d_in[8];
    const float* Wpost = (const float*)d_in[9];
    const float* bpost = (const float*)d_in[10];
    const float* Wm1   = (const float*)d_in[11];
    const float* bm1   = (const float*)d_in[12];
    const float* Wm2   = (const float*)d_in[13];
    const float* bm2   = (const float*)d_in[14];
    const float* Wm3   = (const float*)d_in[15];
    const float* bm3   = (const float*)d_in[16];
    float* out = (float*)d_out;

    float* ws = (float*)d_ws;
    // layout (4-byte units); zero region = [0, 500064)
    float* ismacro = ws;                        //   200,000
    float* sum_all = ws + 200000;               //        64
    int*   cnt     = (int*)(ws + 200064);       //   300,000 (combined node+he counts)
    // end zero region (500,064)
    int*   row_ptr  = (int*)(ws + 500064);      //   300,001
    int*   partials = (int*)(ws + 800096);      //       300
    int*   csr      = (int*)(ws + 800396);      // 2,000,000 ([0,NNZ): node side, [NNZ,2NNZ): he side)
    float* e_att    = ws + 2800396;             //   100,000
    float* xn_att   = ws + 2900396;             //   200,000
    float* e_feat   = ws + 3100396;             // 6,400,000
    float* xl       = ws + 9500396;             // 12,800,000 (reused as hx)
    // total: 22,300,396 floats ~= 89.2 MB

    const int* nidx = edge;
    const int* hidx = edge + NNZ;

    fill_f32<<<512, 256, 0, stream>>>(ws, 500064LL, 0.f);
    k_ismacro<<<2, 256, 0, stream>>>(macro, ismacro);
    k_count<<<2048, 256, 0, stream>>>(nidx, hidx, cnt);
    k_xl<<<2048, 256, 0, stream>>>(x, fake_pos, ismacro, W1, b1, att, xl, xn_att);
    k_scan1<<<NB_SCAN, 256, 0, stream>>>(cnt, row_ptr, partials);
    k_scan2<<<1, 512, 0, stream>>>(partials);
    k_scan3<<<NB_SCAN, 256, 0, stream>>>(row_ptr, partials);
    k_scatter<<<2048, 256, 0, stream>>>(nidx, hidx, row_ptr, cnt, csr);
    k_he_agg<<<1024, 256, 0, stream>>>(row_ptr, csr, nidx, pinf, Wpin, xl, att, e_feat, e_att);
    k_fused<<<2048, 256, 0, stream>>>(row_ptr, csr, xn_att, e_att, e_feat, Wpost, bpost, xl, sum_all);
    k_final<<<1, 256, 0, stream>>>(xl, macro, sum_all, Wm1, bm1, Wm2, bm2, Wm3, bm3, out);
}

// Round 4
// 776.906 us; speedup vs baseline: 1.3061x; 1.2740x over previous
//
#include <hip/hip_runtime.h>
#include <math.h>

#define N_NODES 200000
#define N_HE    100000
#define NNZ     1000000
#define F_RAW   29
#define N_MACRO 512
#define SLOPE   0.1f
#define L_TOTAL (N_NODES + N_HE)   // 300000 combined counters
#define NB_SCAN 293                // ceil(300000/1024)

__device__ __forceinline__ float lrelu(float v) { return v >= 0.f ? v : SLOPE * v; }

// ---------- fills ----------
__global__ __launch_bounds__(256) void fill_f32(float* p, long long n, float v) {
    long long i = (long long)blockIdx.x * blockDim.x + threadIdx.x;
    long long st = (long long)gridDim.x * blockDim.x;
    for (; i < n; i += st) p[i] = v;
}

__global__ __launch_bounds__(256) void k_ismacro(const int* __restrict__ mi,
                                                 float* __restrict__ ismacro, int* __restrict__ mcount) {
    int i = blockIdx.x * blockDim.x + threadIdx.x;
    if (i < N_MACRO) {
        ismacro[mi[i]] = 1.0f;          // duplicates collapse (feature flag)
        atomicAdd(&mcount[mi[i]], 1);   // duplicates counted (pool weight)
    }
}

// ---------- K0: xl = h @ W1 + b1 ; xn_att = xl . att[:64] ----------
__global__ __launch_bounds__(256) void k_xl(
    const float* __restrict__ x, const float* __restrict__ fake_pos,
    const float* __restrict__ ismacro,
    const float* __restrict__ W1, const float* __restrict__ b1,
    const float* __restrict__ att,
    float* __restrict__ xl, float* __restrict__ xn_att)
{
    __shared__ float sW[32 * 64];
    __shared__ float sb[64];
    __shared__ float sa[64];
    for (int i = threadIdx.x; i < 32 * 64; i += 256) sW[i] = W1[i];
    if (threadIdx.x < 64) { sb[threadIdx.x] = b1[threadIdx.x]; sa[threadIdx.x] = att[threadIdx.x]; }
    __syncthreads();
    const int lane = threadIdx.x & 63;
    const int wave = threadIdx.x >> 6;
    int w = blockIdx.x * 4 + wave;
    int nw = gridDim.x * 4;
    for (int n = w; n < N_NODES; n += nw) {
        float acc = sb[lane];
        const float* xr = x + (size_t)n * F_RAW;
        #pragma unroll
        for (int k = 0; k < F_RAW; k++) acc += xr[k] * sW[k * 64 + lane];
        acc += fake_pos[2 * n]     * sW[29 * 64 + lane];
        acc += fake_pos[2 * n + 1] * sW[30 * 64 + lane];
        acc += ismacro[n]          * sW[31 * 64 + lane];
        xl[(size_t)n * 64 + lane] = acc;
        float r = acc * sa[lane];
        #pragma unroll
        for (int o = 32; o > 0; o >>= 1) r += __shfl_down(r, o, 64);
        if (lane == 0) xn_att[n] = r;
    }
}

// ---------- count pins per node and per hyperedge (combined array) ----------
__global__ __launch_bounds__(256) void k_count(
    const int* __restrict__ nidx, const int* __restrict__ hidx, int* __restrict__ cnt)
{
    int i = blockIdx.x * blockDim.x + threadIdx.x;
    int st = gridDim.x * blockDim.x;
    for (int p = i; p < NNZ; p += st) {
        atomicAdd(&cnt[nidx[p]], 1);
        atomicAdd(&cnt[N_NODES + hidx[p]], 1);
    }
}

// ---------- scan of cnt (length L_TOTAL) -> row_ptr ----------
__global__ __launch_bounds__(256) void k_scan1(const int* __restrict__ cnt,
                                               int* __restrict__ row_ptr, int* __restrict__ partials)
{
    __shared__ int sA[256], sB[256];
    const int t = threadIdx.x;
    const int base = blockIdx.x * 1024 + t * 4;
    int v0 = base + 0 < L_TOTAL ? cnt[base + 0] : 0;
    int v1 = base + 1 < L_TOTAL ? cnt[base + 1] : 0;
    int v2 = base + 2 < L_TOTAL ? cnt[base + 2] : 0;
    int v3 = base + 3 < L_TOTAL ? cnt[base + 3] : 0;
    sA[t] = v0 + v1 + v2 + v3;
    __syncthreads();
    int* src = sA; int* dst = sB;
    for (int off = 1; off < 256; off <<= 1) {
        int v = src[t];
        if (t >= off) v += src[t - off];
        dst[t] = v;
        __syncthreads();
        int* tmp = src; src = dst; dst = tmp;
    }
    int excl = t > 0 ? src[t - 1] : 0;
    if (base + 0 < L_TOTAL) row_ptr[base + 0] = excl;
    if (base + 1 < L_TOTAL) row_ptr[base + 1] = excl + v0;
    if (base + 2 < L_TOTAL) row_ptr[base + 2] = excl + v0 + v1;
    if (base + 3 < L_TOTAL) row_ptr[base + 3] = excl + v0 + v1 + v2;
    if (t == 255) partials[blockIdx.x] = src[255];
}

__global__ __launch_bounds__(512) void k_scan2(int* __restrict__ partials)
{
    __shared__ int sA[512], sB[512];
    const int t = threadIdx.x;
    sA[t] = t < NB_SCAN ? partials[t] : 0;
    __syncthreads();
    int* src = sA; int* dst = sB;
    for (int off = 1; off < 512; off <<= 1) {
        int v = src[t];
        if (t >= off) v += src[t - off];
        dst[t] = v;
        __syncthreads();
        int* tmp = src; src = dst; dst = tmp;
    }
    if (t < NB_SCAN) partials[t] = t > 0 ? src[t - 1] : 0;
    if (t == 0) partials[NB_SCAN] = src[511];
}

__global__ __launch_bounds__(256) void k_scan3(int* __restrict__ row_ptr, const int* __restrict__ partials)
{
    const int base = blockIdx.x * 1024 + threadIdx.x * 4;
    int add = partials[blockIdx.x];
    #pragma unroll
    for (int k = 0; k < 4; k++)
        if (base + k < L_TOTAL) row_ptr[base + k] += add;
    if (blockIdx.x == 0 && threadIdx.x == 0) row_ptr[L_TOTAL] = partials[NB_SCAN];
}

// ---------- scatter pins into both CSRs (node side: he id; he side: pin id) ----------
__global__ __launch_bounds__(256) void k_scatter(
    const int* __restrict__ nidx, const int* __restrict__ hidx,
    const int* __restrict__ row_ptr, int* __restrict__ cnt, int* __restrict__ csr)
{
    int i = blockIdx.x * blockDim.x + threadIdx.x;
    int st = gridDim.x * blockDim.x;
    for (int p = i; p < NNZ; p += st) {
        int n = nidx[p], e = hidx[p];
        int pn = row_ptr[n] + atomicSub(&cnt[n], 1) - 1;
        csr[pn] = e;
        int pe = row_ptr[N_NODES + e] + atomicSub(&cnt[N_NODES + e], 1) - 1;
        csr[pe] = p;
    }
}

// ---------- he-side gather: e_feat mean + e_att dot (no atomics) ----------
__global__ __launch_bounds__(256) void k_he_agg(
    const int* __restrict__ row_ptr, const int* __restrict__ csr,
    const int* __restrict__ nidx,
    const float* __restrict__ pinf, const float* __restrict__ Wpin,
    const float* __restrict__ xl, const float* __restrict__ att,
    float* __restrict__ e_feat, float* __restrict__ e_att)
{
    const int lane = threadIdx.x & 63;
    int w = (blockIdx.x * blockDim.x + threadIdx.x) >> 6;
    int nw = (gridDim.x * blockDim.x) >> 6;
    float w0 = Wpin[lane], w1 = Wpin[64 + lane], w2 = Wpin[128 + lane], w3 = Wpin[192 + lane];
    float ac = att[64 + lane];
    const float4* pf4 = (const float4*)pinf;
    for (int e = w; e < N_HE; e += nw) {
        int start = row_ptr[N_NODES + e];
        int deg = row_ptr[N_NODES + e + 1] - start;
        float acc = 0.f;
        int t = 0;
        for (; t + 4 <= deg; t += 4) {
            int p0 = csr[start + t], p1 = csr[start + t + 1];
            int p2 = csr[start + t + 2], p3 = csr[start + t + 3];
            int n0 = nidx[p0], n1 = nidx[p1], n2 = nidx[p2], n3 = nidx[p3];
            float v0 = xl[(size_t)n0 * 64 + lane];
            float v1 = xl[(size_t)n1 * 64 + lane];
            float v2 = xl[(size_t)n2 * 64 + lane];
            float v3 = xl[(size_t)n3 * 64 + lane];
            float4 q0 = pf4[p0], q1 = pf4[p1], q2 = pf4[p2], q3 = pf4[p3];
            acc += v0 + q0.x * w0 + q0.y * w1 + q0.z * w2 + q0.w * w3;
            acc += v1 + q1.x * w0 + q1.y * w1 + q1.z * w2 + q1.w * w3;
            acc += v2 + q2.x * w0 + q2.y * w1 + q2.z * w2 + q2.w * w3;
            acc += v3 + q3.x * w0 + q3.y * w1 + q3.z * w2 + q3.w * w3;
        }
        for (; t < deg; t++) {
            int p = csr[start + t];
            int n = nidx[p];
            float4 q = pf4[p];
            acc += xl[(size_t)n * 64 + lane] + q.x * w0 + q.y * w1 + q.z * w2 + q.w * w3;
        }
        float d = (float)(deg > 0 ? deg : 1);
        float v = acc / d;
        e_feat[(size_t)e * 64 + lane] = v;
        float r = v * ac;
        #pragma unroll
        for (int o = 32; o > 0; o >>= 1) r += __shfl_down(r, o, 64);
        if (lane == 0) e_att[e] = r;
    }
}

// ---------- fused single-pass softmax+PNA + post GEMM + lrelu + both pools ----------
// Softmax max-subtraction dropped (shift-invariant; |a|<~5 so exp is fp32-safe).
// Unnormalized accumulation: msg_p = w_p*v_p/D with D=sum w_p known post-pass;
// max/min commute with the positive 1/D scale.
__global__ __launch_bounds__(256) void k_fused(
    const int* __restrict__ row_ptr, const int* __restrict__ csr,
    const float* __restrict__ xn_att, const float* __restrict__ e_att,
    const float* __restrict__ e_feat,
    const float* __restrict__ Wpost, const float* __restrict__ bpost,
    const int* __restrict__ mcount,
    float* __restrict__ sum_all, float* __restrict__ sum_mac)
{
    __shared__ float scat[32 * 260];   // 32 nodes x 256 cat, stride 260
    __shared__ float sred[16][68];
    const int lane = threadIdx.x & 63;
    const int wave = threadIdx.x >> 6;
    const int cg = threadIdx.x & 15;   // phase B: channels 4cg..4cg+3
    const int ng = threadIdx.x >> 4;   // phase B: nodes 2ng, 2ng+1
    const float4* Wp4 = (const float4*)Wpost;
    float4 bp = ((const float4*)bpost)[cg];
    float4 pool = make_float4(0.f, 0.f, 0.f, 0.f);
    float4 pmac = make_float4(0.f, 0.f, 0.f, 0.f);
    const int nbatches = N_NODES / 32;  // 6250
    for (int b = blockIdx.x; b < nbatches; b += gridDim.x) {
        const int base = b * 32;
        __syncthreads();
        // ---- phase A: 8 nodes per wave, one pass over pins ----
        for (int i = 0; i < 8; i++) {
            int j = wave * 8 + i;
            int n = base + j;
            int start = row_ptr[n];
            int deg = row_ptr[n + 1] - start;
            float xn = xn_att[n];
            float sw = 0.f, s = 0.f, sq = 0.f, mx = -INFINITY, mn = INFINITY;
            int t = 0;
            for (; t + 4 <= deg; t += 4) {
                int e0 = csr[start + t],     e1 = csr[start + t + 1];
                int e2 = csr[start + t + 2], e3 = csr[start + t + 3];
                float w0 = __expf(lrelu(xn + e_att[e0]));
                float w1 = __expf(lrelu(xn + e_att[e1]));
                float w2 = __expf(lrelu(xn + e_att[e2]));
                float w3 = __expf(lrelu(xn + e_att[e3]));
                float v0 = e_feat[(size_t)e0 * 64 + lane] * w0;
                float v1 = e_feat[(size_t)e1 * 64 + lane] * w1;
                float v2 = e_feat[(size_t)e2 * 64 + lane] * w2;
                float v3 = e_feat[(size_t)e3 * 64 + lane] * w3;
                sw += w0 + w1 + w2 + w3;
                s  += v0 + v1 + v2 + v3;
                sq += v0 * v0 + v1 * v1 + v2 * v2 + v3 * v3;
                mx = fmaxf(fmaxf(mx, v0), fmaxf(fmaxf(v1, v2), v3));
                mn = fminf(fminf(mn, v0), fminf(fminf(v1, v2), v3));
            }
            for (; t < deg; t++) {
                int e = csr[start + t];
                float w = __expf(lrelu(xn + e_att[e]));
                float v = e_feat[(size_t)e * 64 + lane] * w;
                sw += w; s += v; sq += v * v;
                mx = fmaxf(mx, v); mn = fminf(mn, v);
            }
            float invD = 1.f / (sw + 1e-16f);
            float dc = (float)(deg > 0 ? deg : 1);
            float mean = s * invD / dc;
            float sqm  = sq * invD * invD / dc;
            float stdv = sqrtf(fmaxf(sqm - mean * mean, 0.f) + 1e-12f);
            float* row = &scat[j * 260];
            row[lane]       = mean;
            row[64 + lane]  = deg > 0 ? mx * invD : 0.f;
            row[128 + lane] = deg > 0 ? mn * invD : 0.f;
            row[192 + lane] = stdv;
        }
        __syncthreads();
        // ---- phase B: 2 nodes x 4 ch per thread, W from global (L1-hot) ----
        float4 a0 = bp, a1 = bp;
        const float* r0 = &scat[(2 * ng) * 260];
        const float* r1 = &scat[(2 * ng + 1) * 260];
        #pragma unroll 2
        for (int k = 0; k < 256; k += 4) {
            float4 c0 = *(const float4*)&r0[k];
            float4 c1 = *(const float4*)&r1[k];
            float4 w0 = Wp4[(k + 0) * 16 + cg];
            float4 w1 = Wp4[(k + 1) * 16 + cg];
            float4 w2 = Wp4[(k + 2) * 16 + cg];
            float4 w3 = Wp4[(k + 3) * 16 + cg];
            a0.x += c0.x * w0.x + c0.y * w1.x + c0.z * w2.x + c0.w * w3.x;
            a0.y += c0.x * w0.y + c0.y * w1.y + c0.z * w2.y + c0.w * w3.y;
            a0.z += c0.x * w0.z + c0.y * w1.z + c0.z * w2.z + c0.w * w3.z;
            a0.w += c0.x * w0.w + c0.y * w1.w + c0.z * w2.w + c0.w * w3.w;
            a1.x += c1.x * w0.x + c1.y * w1.x + c1.z * w2.x + c1.w * w3.x;
            a1.y += c1.x * w0.y + c1.y * w1.y + c1.z * w2.y + c1.w * w3.y;
            a1.z += c1.x * w0.z + c1.y * w1.z + c1.z * w2.z + c1.w * w3.z;
            a1.w += c1.x * w0.w + c1.y * w1.w + c1.z * w2.w + c1.w * w3.w;
        }
        float4 h0, h1;
        h0.x = lrelu(a0.x); h0.y = lrelu(a0.y); h0.z = lrelu(a0.z); h0.w = lrelu(a0.w);
        h1.x = lrelu(a1.x); h1.y = lrelu(a1.y); h1.z = lrelu(a1.z); h1.w = lrelu(a1.w);
        float c0 = (float)mcount[base + 2 * ng];
        float c1 = (float)mcount[base + 2 * ng + 1];
        pool.x += h0.x + h1.x; pool.y += h0.y + h1.y;
        pool.z += h0.z + h1.z; pool.w += h0.w + h1.w;
        pmac.x += c0 * h0.x + c1 * h1.x; pmac.y += c0 * h0.y + c1 * h1.y;
        pmac.z += c0 * h0.z + c1 * h1.z; pmac.w += c0 * h0.w + c1 * h1.w;
    }
    // ---- block reduction of both pools ----
    __syncthreads();
    sred[ng][4 * cg + 0] = pool.x;
    sred[ng][4 * cg + 1] = pool.y;
    sred[ng][4 * cg + 2] = pool.z;
    sred[ng][4 * cg + 3] = pool.w;
    __syncthreads();
    if (threadIdx.x < 64) {
        float t = 0.f;
        #pragma unroll
        for (int r = 0; r < 16; r++) t += sred[r][threadIdx.x];
        atomicAdd(&sum_all[threadIdx.x], t);
    }
    __syncthreads();
    sred[ng][4 * cg + 0] = pmac.x;
    sred[ng][4 * cg + 1] = pmac.y;
    sred[ng][4 * cg + 2] = pmac.z;
    sred[ng][4 * cg + 3] = pmac.w;
    __syncthreads();
    if (threadIdx.x < 64) {
        float t = 0.f;
        #pragma unroll
        for (int r = 0; r < 16; r++) t += sred[r][threadIdx.x];
        atomicAdd(&sum_mac[threadIdx.x], t);
    }
}

// ---------- tiny MLP head from the two pooled vectors ----------
__global__ __launch_bounds__(256) void k_final(
    const float* __restrict__ sum_all, const float* __restrict__ sum_mac,
    const float* __restrict__ Wm1, const float* __restrict__ bm1,
    const float* __restrict__ Wm2, const float* __restrict__ bm2,
    const float* __restrict__ Wm3, const float* __restrict__ bm3,
    float* __restrict__ out)
{
    __shared__ float spool[128];
    __shared__ float z1[64];
    __shared__ float z2[32];
    if (threadIdx.x < 64) {
        spool[threadIdx.x]      = sum_mac[threadIdx.x] / (float)N_MACRO;
        spool[64 + threadIdx.x] = sum_all[threadIdx.x] / (float)N_NODES;
    }
    __syncthreads();
    if (threadIdx.x < 64) {
        int j = threadIdx.x;
        float a = bm1[j];
        #pragma unroll 4
        for (int k = 0; k < 128; k++) a += spool[k] * Wm1[k * 64 + j];
        z1[j] = lrelu(a);
    }
    __syncthreads();
    if (threadIdx.x < 32) {
        int j = threadIdx.x;
        float a = bm2[j];
        #pragma unroll 4
        for (int k = 0; k < 64; k++) a += z1[k] * Wm2[k * 32 + j];
        z2[j] = lrelu(a);
    }
    __syncthreads();
    if (threadIdx.x == 0) {
        float a = bm3[0];
        #pragma unroll
        for (int k = 0; k < 32; k++) a += z2[k] * Wm3[k];
        out[0] = a;
    }
}

// ---------- launch ----------
extern "C" void kernel_launch(void* const* d_in, const int* in_sizes, int n_in,
                              void* d_out, int out_size, void* d_ws, size_t ws_size,
                              hipStream_t stream)
{
    const float* x        = (const float*)d_in[0];
    const float* fake_pos = (const float*)d_in[1];
    const int*   edge     = (const int*)d_in[2];
    const float* pinf     = (const float*)d_in[3];
    const int*   macro    = (const int*)d_in[4];
    const float* W1    = (const float*)d_in[5];
    const float* b1    = (const float*)d_in[6];
    const float* Wpin  = (const float*)d_in[7];
    const float* att   = (const float*)d_in[8];
    const float* Wpost = (const float*)d_in[9];
    const float* bpost = (const float*)d_in[10];
    const float* Wm1   = (const float*)d_in[11];
    const float* bm1   = (const float*)d_in[12];
    const float* Wm2   = (const float*)d_in[13];
    const float* bm2   = (const float*)d_in[14];
    const float* Wm3   = (const float*)d_in[15];
    const float* bm3   = (const float*)d_in[16];
    float* out = (float*)d_out;

    float* ws = (float*)d_ws;
    // layout (4-byte units); zero region = [0, 700128)
    float* ismacro = ws;                        //   200,000
    float* sum_all = ws + 200000;               //        64
    float* sum_mac = ws + 200064;               //        64
    int*   mcount  = (int*)(ws + 200128);       //   200,000
    int*   cnt     = (int*)(ws + 400128);       //   300,000 (combined node+he counts)
    // end zero region (700,128)
    int*   row_ptr  = (int*)(ws + 700128);      //   300,001
    int*   partials = (int*)(ws + 1000132);     //       300
    int*   csr      = (int*)(ws + 1000432);     // 2,000,000 ([0,NNZ): node side, [NNZ,2NNZ): he side)
    float* e_att    = ws + 3000432;             //   100,000
    float* xn_att   = ws + 3100432;             //   200,000
    float* e_feat   = ws + 3300432;             // 6,400,000
    float* xl       = ws + 9700432;             // 12,800,000
    // total: 22,500,432 floats ~= 90.0 MB

    const int* nidx = edge;
    const int* hidx = edge + NNZ;

    fill_f32<<<512, 256, 0, stream>>>(ws, 700128LL, 0.f);
    k_ismacro<<<2, 256, 0, stream>>>(macro, ismacro, mcount);
    k_count<<<2048, 256, 0, stream>>>(nidx, hidx, cnt);
    k_xl<<<2048, 256, 0, stream>>>(x, fake_pos, ismacro, W1, b1, att, xl, xn_att);
    k_scan1<<<NB_SCAN, 256, 0, stream>>>(cnt, row_ptr, partials);
    k_scan2<<<1, 512, 0, stream>>>(partials);
    k_scan3<<<NB_SCAN, 256, 0, stream>>>(row_ptr, partials);
    k_scatter<<<2048, 256, 0, stream>>>(nidx, hidx, row_ptr, cnt, csr);
    k_he_agg<<<1024, 256, 0, stream>>>(row_ptr, csr, nidx, pinf, Wpin, xl, att, e_feat, e_att);
    k_fused<<<1024, 256, 0, stream>>>(row_ptr, csr, xn_att, e_att, e_feat, Wpost, bpost,
                                      mcount, sum_all, sum_mac);
    k_final<<<1, 256, 0, stream>>>(sum_all, sum_mac, Wm1, bm1, Wm2, bm2, Wm3, bm3, out);
}